// Round 7
// baseline (654.943 us; speedup 1.0000x reference)
//
#include <hip/hip_runtime.h>
#include <hip/hip_fp16.h>

#define EMBED 128
#define CHUNK 16
#define T_TILE 4096
#define NB_SH 10            // 1024 rows per bucket; NB = ceil(N/1024) <= 256

// ---------------- CSR build ----------------

__global__ void hist_kernel(const int* __restrict__ row, int* __restrict__ hist, int E4) {
    int i = blockIdx.x * blockDim.x + threadIdx.x;
    if (i < E4) {
        int4 r = ((const int4*)row)[i];
        atomicAdd(&hist[r.x], 1);
        atomicAdd(&hist[r.y], 1);
        atomicAdd(&hist[r.z], 1);
        atomicAdd(&hist[r.w], 1);
    }
}

__global__ void scan1(const int* __restrict__ hist, int* __restrict__ rs,
                      int* __restrict__ bsums, int N) {
    __shared__ int s[256];
    int i = blockIdx.x * 256 + threadIdx.x;
    int x = (i < N) ? hist[i] : 0;
    s[threadIdx.x] = x;
    __syncthreads();
    for (int off = 1; off < 256; off <<= 1) {
        int t = (threadIdx.x >= off) ? s[threadIdx.x - off] : 0;
        __syncthreads();
        s[threadIdx.x] += t;
        __syncthreads();
    }
    if (i < N) rs[i] = s[threadIdx.x] - x;
    if (threadIdx.x == 255) bsums[blockIdx.x] = s[255];
}

__global__ void scan2(int* __restrict__ bsums, int nb) {
    __shared__ int s[1024];
    __shared__ int carry;
    if (threadIdx.x == 0) carry = 0;
    __syncthreads();
    for (int base = 0; base < nb; base += 1024) {
        int i = base + threadIdx.x;
        int x = (i < nb) ? bsums[i] : 0;
        s[threadIdx.x] = x;
        __syncthreads();
        for (int off = 1; off < 1024; off <<= 1) {
            int t = (threadIdx.x >= off) ? s[threadIdx.x - off] : 0;
            __syncthreads();
            s[threadIdx.x] += t;
            __syncthreads();
        }
        if (i < nb) bsums[i] = s[threadIdx.x] - x + carry;
        __syncthreads();
        if (threadIdx.x == 0) carry += s[1023];
        __syncthreads();
    }
}

__global__ void scan3(int* __restrict__ rs, const int* __restrict__ bsums,
                      int* __restrict__ cursor, int N, int E) {
    int i = blockIdx.x * blockDim.x + threadIdx.x;
    if (i < N) {
        int v = rs[i] + bsums[i >> 8];
        rs[i] = v;
        cursor[i] = v;
    }
    if (i == 0) rs[N] = E;
}

__global__ void binit(const int* __restrict__ rs, int* __restrict__ bcursor,
                      int N, int nbuckets) {
    int b = blockIdx.x * blockDim.x + threadIdx.x;
    if (b < nbuckets) {
        int r = b << NB_SH;
        if (r > N) r = N;
        bcursor[b] = rs[r];
    }
}

// Pass A: tile-local counting sort into bucket regions (contiguous runs of writes)
__global__ __launch_bounds__(256) void passA(const int* __restrict__ row,
                                             const int* __restrict__ col,
                                             const float* __restrict__ val,
                                             int* __restrict__ bcursor,
                                             long long* __restrict__ bedges, int E) {
    __shared__ int sh_scan[256];    // inclusive scan (frozen after scan)
    __shared__ int sh_start[256];   // frozen exclusive start
    __shared__ int sh_cur[256];     // running LDS cursor
    __shared__ int sh_base[256];    // global base per bucket
    __shared__ long long sh_data[T_TILE];
    __shared__ int sh_gpos[T_TILE];
    const int t0  = blockIdx.x * T_TILE;
    const int tid = threadIdx.x;

    sh_scan[tid] = 0;
    __syncthreads();
    #pragma unroll
    for (int i = 0; i < T_TILE / 256; ++i) {
        int idx = t0 + i * 256 + tid;
        if (idx < E) atomicAdd(&sh_scan[row[idx] >> NB_SH], 1);
    }
    __syncthreads();
    int x = sh_scan[tid];
    __syncthreads();
    for (int off = 1; off < 256; off <<= 1) {
        int t = (tid >= off) ? sh_scan[tid - off] : 0;
        __syncthreads();
        sh_scan[tid] += t;
        __syncthreads();
    }
    int excl = sh_scan[tid] - x;
    sh_start[tid] = excl;
    sh_cur[tid]   = excl;
    sh_base[tid]  = (x > 0) ? atomicAdd(&bcursor[tid], x) : 0;
    __syncthreads();
    #pragma unroll
    for (int i = 0; i < T_TILE / 256; ++i) {
        int idx = t0 + i * 256 + tid;
        if (idx < E) {
            int   r = row[idx];
            int   c = col[idx];
            float v = val[idx];
            int   b = r >> NB_SH;
            int   p = atomicAdd(&sh_cur[b], 1);
            unsigned lo = (unsigned)(((r & ((1 << NB_SH) - 1)) << 18) | c);
            sh_data[p] = ((long long)__float_as_int(v) << 32) | (long long)lo;
            sh_gpos[p] = sh_base[b] + (p - sh_start[b]);
        }
    }
    __syncthreads();
    int tot = sh_scan[255];
    for (int p = tid; p < tot; p += 256) {
        bedges[sh_gpos[p]] = sh_data[p];
    }
}

// Pass B: one block per bucket; resolve exact CSR slot, write final edges
__global__ __launch_bounds__(1024) void passB(const int* __restrict__ rs,
                                              const long long* __restrict__ bedges,
                                              int* __restrict__ cursor,
                                              int2* __restrict__ edges, int N) {
    int b = blockIdx.x;
    int base = b << NB_SH;
    int endRow = base + (1 << NB_SH);
    if (endRow > N) endRow = N;
    int s = rs[base], e = rs[endRow];
    for (int k = s + threadIdx.x; k < e; k += 1024) {
        long long be = bedges[k];
        unsigned lo = (unsigned)be;
        int r = base + (int)(lo >> 18);
        int c = (int)(lo & 0x3FFFF);
        int pos = atomicAdd(&cursor[r], 1);
        edges[pos] = make_int2(c, (int)(be >> 32));
    }
}

// ---------------- fp32 -> fp16 convert (8 elems/thread, both tables) ----------------

__global__ void f32_to_f16_all(const float* __restrict__ uE, const float* __restrict__ iE,
                               __half* __restrict__ dst, int nu8, int ntot8) {
    int i = blockIdx.x * blockDim.x + threadIdx.x;
    if (i >= ntot8) return;
    const float* src = (i < nu8) ? (uE + (size_t)i * 8)
                                 : (iE + (size_t)(i - nu8) * 8);
    float4 a = ((const float4*)src)[0];
    float4 b = ((const float4*)src)[1];
    __half2 h0 = __floats2half2_rn(a.x, a.y);
    __half2 h1 = __floats2half2_rn(a.z, a.w);
    __half2 h2 = __floats2half2_rn(b.x, b.y);
    __half2 h3 = __floats2half2_rn(b.z, b.w);
    uint4 o;
    o.x = *(unsigned int*)&h0;
    o.y = *(unsigned int*)&h1;
    o.z = *(unsigned int*)&h2;
    o.w = *(unsigned int*)&h3;
    ((uint4*)dst)[i] = o;
}

// ---------------- SpMM: 2 rows/wave (32 lanes each), fp16 h, fp32 acc ----------------
// fma_mix pattern: fmaf((float)h16, v, acc) -> v_fma_mix_f32 (cvt+fma fused).

__global__ void spmm_kernel(const int* __restrict__ rs, const int2* __restrict__ edges,
                            const __half* __restrict__ hin, __half* __restrict__ hout,
                            int N) {
    int gid  = blockIdx.x * blockDim.x + threadIdx.x;
    int wave = gid >> 6;
    int lane = threadIdx.x & 63;
    int half = lane >> 5;
    int l32  = lane & 31;
    int row  = wave * 2 + half;
    if (row >= N) return;
    int s = rs[row], e = rs[row + 1];
    float4 acc = make_float4(0.f, 0.f, 0.f, 0.f);
    for (int k = s; k < e; k += CHUNK) {
        uint2 raw[CHUNK];
        float vv[CHUNK];
        #pragma unroll
        for (int j = 0; j < CHUNK; ++j) {
            bool ok  = (k + j) < e;
            int  idx = ok ? (k + j) : s;
            int2 ed  = edges[idx];
            vv[j]    = ok ? __int_as_float(ed.y) : 0.f;
            raw[j]   = *(const uint2*)(hin + (size_t)ed.x * EMBED + 4 * l32);
        }
        #pragma unroll
        for (int j = 0; j < CHUNK; ++j) {
            __half2 h01 = *(__half2*)&raw[j].x;
            __half2 h23 = *(__half2*)&raw[j].y;
            acc.x = fmaf(__half2float(h01.x), vv[j], acc.x);
            acc.y = fmaf(__half2float(h01.y), vv[j], acc.y);
            acc.z = fmaf(__half2float(h23.x), vv[j], acc.z);
            acc.w = fmaf(__half2float(h23.y), vv[j], acc.w);
        }
    }
    __half2 o0 = __floats2half2_rn(acc.x, acc.y);
    __half2 o1 = __floats2half2_rn(acc.z, acc.w);
    uint2 o;
    o.x = *(unsigned int*)&o0;
    o.y = *(unsigned int*)&o1;
    *(uint2*)(hout + (size_t)row * EMBED + 4 * l32) = o;
}

// ---------------- fused tail: per pair b, half0 = u-row, half1 = v-row ----------------
// acc = emb(fp32) + h1 + h2 + (L @ h2)[row]; dot across halves via shfl_xor(32).

__global__ void spmm_pair(const int* __restrict__ rs, const int2* __restrict__ edges,
                          const __half* __restrict__ h1, const __half* __restrict__ h2,
                          const float* __restrict__ uE, const float* __restrict__ iE,
                          const int* __restrict__ uIdx, const int* __restrict__ vIdx,
                          float* __restrict__ out, int B, int userNum) {
    int gid  = blockIdx.x * blockDim.x + threadIdx.x;
    int wave = gid >> 6;
    int lane = threadIdx.x & 63;
    int half = lane >> 5;
    int l32  = lane & 31;
    if (wave >= B) return;
    int row;
    const float* emb;
    if (half == 0) {
        int u = uIdx[wave];
        row = u;
        emb = uE + (size_t)u * EMBED;
    } else {
        int it = vIdx[wave];
        row = userNum + it;
        emb = iE + (size_t)it * EMBED;
    }
    float4 acc = *(const float4*)(emb + 4 * l32);
    size_t ro = (size_t)row * EMBED + 4 * l32;
    uint2 r1 = *(const uint2*)(h1 + ro);
    uint2 r2 = *(const uint2*)(h2 + ro);
    {
        __half2 a0 = *(__half2*)&r1.x, a1 = *(__half2*)&r1.y;
        __half2 b0 = *(__half2*)&r2.x, b1 = *(__half2*)&r2.y;
        acc.x += __half2float(a0.x) + __half2float(b0.x);
        acc.y += __half2float(a0.y) + __half2float(b0.y);
        acc.z += __half2float(a1.x) + __half2float(b1.x);
        acc.w += __half2float(a1.y) + __half2float(b1.y);
    }
    int s = rs[row], e = rs[row + 1];
    for (int k = s; k < e; k += CHUNK) {
        uint2 raw[CHUNK];
        float vv[CHUNK];
        #pragma unroll
        for (int j = 0; j < CHUNK; ++j) {
            bool ok  = (k + j) < e;
            int  idx = ok ? (k + j) : s;
            int2 ed  = edges[idx];
            vv[j]    = ok ? __int_as_float(ed.y) : 0.f;
            raw[j]   = *(const uint2*)(h2 + (size_t)ed.x * EMBED + 4 * l32);
        }
        #pragma unroll
        for (int j = 0; j < CHUNK; ++j) {
            __half2 h01 = *(__half2*)&raw[j].x;
            __half2 h23 = *(__half2*)&raw[j].y;
            acc.x = fmaf(__half2float(h01.x), vv[j], acc.x);
            acc.y = fmaf(__half2float(h01.y), vv[j], acc.y);
            acc.z = fmaf(__half2float(h23.x), vv[j], acc.z);
            acc.w = fmaf(__half2float(h23.y), vv[j], acc.w);
        }
    }
    // cross-half dot: lane l gets the other side's 4 cols
    float ox = __shfl_xor(acc.x, 32);
    float oy = __shfl_xor(acc.y, 32);
    float oz = __shfl_xor(acc.z, 32);
    float ow = __shfl_xor(acc.w, 32);
    float sdot = acc.x * ox + acc.y * oy + acc.z * oz + acc.w * ow;
    #pragma unroll
    for (int off = 16; off > 0; off >>= 1) sdot += __shfl_down(sdot, off, 32);
    // both halves summed the same products -> reduce over full wave doubles it
    sdot += __shfl_down(sdot, 32);
    if (lane == 0) out[wave] = sdot * (1.f / 32.f);   // (acc/4)·(acc/4), x2 halves
}

// ---------------- launch ----------------

extern "C" void kernel_launch(void* const* d_in, const int* in_sizes, int n_in,
                              void* d_out, int out_size, void* d_ws, size_t ws_size,
                              hipStream_t stream) {
    const float* uE      = (const float*)d_in[0];
    const float* iE      = (const float*)d_in[1];
    const float* L_val   = (const float*)d_in[2];
    const int*   L_row   = (const int*)d_in[3];
    const int*   L_col   = (const int*)d_in[4];
    const int*   userIdx = (const int*)d_in[5];
    const int*   itemIdx = (const int*)d_in[6];

    const int userNum = in_sizes[0] / EMBED;   // 100000
    const int itemNum = in_sizes[1] / EMBED;   // 50000
    const int N = userNum + itemNum;           // 150000
    const int E = in_sizes[2];                 // 2000000
    const int B = in_sizes[5];                 // 16384
    float* out = (float*)d_out;

    char* ws = (char*)d_ws;
    size_t off = 0;
    auto alloc = [&](size_t bytes) -> void* {
        void* p = ws + off;
        off += (bytes + 1023) & ~(size_t)1023;
        return p;
    };
    __half* h0     = (__half*)alloc((size_t)N * EMBED * 2);
    __half* h1     = (__half*)alloc((size_t)N * EMBED * 2);
    __half* h2     = (__half*)alloc((size_t)N * EMBED * 2);
    int2*   edges  = (int2*) alloc((size_t)E * 8);
    long long* bedges = (long long*)alloc((size_t)E * 8);
    int*    rs     = (int*)  alloc((size_t)(N + 1) * 4);
    int*    cursor = (int*)  alloc((size_t)N * 4);
    int*    hist   = (int*)  alloc((size_t)N * 4);
    int*    bsums  = (int*)  alloc(8192);
    int*    bcursor= (int*)  alloc(1024);
    (void)off; (void)ws_size; (void)n_in; (void)out_size;

    const int tb = 256;
    const int NBUCKETS = (N + (1 << NB_SH) - 1) >> NB_SH;   // 147 (<=256 required)

    // CSR build: hist -> scan -> bucket sort (passA) -> exact placement (passB)
    (void)hipMemsetAsync(hist, 0, (size_t)N * 4, stream);
    const int E4 = E / 4;
    hist_kernel<<<(E4 + tb - 1) / tb, tb, 0, stream>>>(L_row, hist, E4);
    const int nb = (N + 255) / 256;
    scan1<<<nb, 256, 0, stream>>>(hist, rs, bsums, N);
    scan2<<<1, 1024, 0, stream>>>(bsums, nb);
    scan3<<<(N + tb - 1) / tb, tb, 0, stream>>>(rs, bsums, cursor, N, E);
    binit<<<1, 256, 0, stream>>>(rs, bcursor, N, NBUCKETS);
    passA<<<(E + T_TILE - 1) / T_TILE, 256, 0, stream>>>(L_row, L_col, L_val,
                                                         bcursor, bedges, E);
    passB<<<NBUCKETS, 1024, 0, stream>>>(rs, bedges, cursor, edges, N);

    // feats -> fp16 (single launch)
    const int nu8 = userNum * EMBED / 8;
    const int ntot8 = N * EMBED / 8;
    f32_to_f16_all<<<(ntot8 + tb - 1) / tb, tb, 0, stream>>>(uE, iE, h0, nu8, ntot8);

    // propagation
    const int spmm_blocks = (N + 7) / 8;        // 8 rows per 256-thread block
    spmm_kernel<<<spmm_blocks, 256, 0, stream>>>(rs, edges, h0, h1, N);
    spmm_kernel<<<spmm_blocks, 256, 0, stream>>>(rs, edges, h1, h2, N);

    // fused layer-3-restricted spmm + layer-sum + dot
    spmm_pair<<<(B + 3) / 4, 256, 0, stream>>>(rs, edges, h1, h2, uE, iE,
                                               userIdx, itemIdx, out, B, userNum);
}

// Round 8
// 550.784 us; speedup vs baseline: 1.1891x; 1.1891x over previous
//
#include <hip/hip_runtime.h>
#include <hip/hip_fp16.h>

#define EMBED 128
#define CHUNK 8
#define T_TILE 4096
#define NB_SH 10            // 1024 rows per bucket; NB = ceil(N/1024) <= 256

// ---------------- CSR build ----------------

__global__ void hist_kernel(const int* __restrict__ row, int* __restrict__ hist, int E4) {
    int i = blockIdx.x * blockDim.x + threadIdx.x;
    if (i < E4) {
        int4 r = ((const int4*)row)[i];
        atomicAdd(&hist[r.x], 1);
        atomicAdd(&hist[r.y], 1);
        atomicAdd(&hist[r.z], 1);
        atomicAdd(&hist[r.w], 1);
    }
}

__global__ void scan1(const int* __restrict__ hist, int* __restrict__ rs,
                      int* __restrict__ bsums, int N) {
    __shared__ int s[256];
    int i = blockIdx.x * 256 + threadIdx.x;
    int x = (i < N) ? hist[i] : 0;
    s[threadIdx.x] = x;
    __syncthreads();
    for (int off = 1; off < 256; off <<= 1) {
        int t = (threadIdx.x >= off) ? s[threadIdx.x - off] : 0;
        __syncthreads();
        s[threadIdx.x] += t;
        __syncthreads();
    }
    if (i < N) rs[i] = s[threadIdx.x] - x;
    if (threadIdx.x == 255) bsums[blockIdx.x] = s[255];
}

__global__ void scan2(int* __restrict__ bsums, int nb) {
    __shared__ int s[1024];
    __shared__ int carry;
    if (threadIdx.x == 0) carry = 0;
    __syncthreads();
    for (int base = 0; base < nb; base += 1024) {
        int i = base + threadIdx.x;
        int x = (i < nb) ? bsums[i] : 0;
        s[threadIdx.x] = x;
        __syncthreads();
        for (int off = 1; off < 1024; off <<= 1) {
            int t = (threadIdx.x >= off) ? s[threadIdx.x - off] : 0;
            __syncthreads();
            s[threadIdx.x] += t;
            __syncthreads();
        }
        if (i < nb) bsums[i] = s[threadIdx.x] - x + carry;
        __syncthreads();
        if (threadIdx.x == 0) carry += s[1023];
        __syncthreads();
    }
}

__global__ void scan3(int* __restrict__ rs, const int* __restrict__ bsums,
                      int* __restrict__ cursor, int N, int E) {
    int i = blockIdx.x * blockDim.x + threadIdx.x;
    if (i < N) {
        int v = rs[i] + bsums[i >> 8];
        rs[i] = v;
        cursor[i] = v;
    }
    if (i == 0) rs[N] = E;
}

__global__ void binit(const int* __restrict__ rs, int* __restrict__ bcursor,
                      int N, int nbuckets) {
    int b = blockIdx.x * blockDim.x + threadIdx.x;
    if (b < nbuckets) {
        int r = b << NB_SH;
        if (r > N) r = N;
        bcursor[b] = rs[r];
    }
}

// Pass A: tile-local counting sort into bucket regions (contiguous runs of writes)
__global__ __launch_bounds__(256) void passA(const int* __restrict__ row,
                                             const int* __restrict__ col,
                                             const float* __restrict__ val,
                                             int* __restrict__ bcursor,
                                             long long* __restrict__ bedges, int E) {
    __shared__ int sh_scan[256];    // inclusive scan (frozen after scan)
    __shared__ int sh_start[256];   // frozen exclusive start
    __shared__ int sh_cur[256];     // running LDS cursor
    __shared__ int sh_base[256];    // global base per bucket
    __shared__ long long sh_data[T_TILE];
    __shared__ int sh_gpos[T_TILE];
    const int t0  = blockIdx.x * T_TILE;
    const int tid = threadIdx.x;

    sh_scan[tid] = 0;
    __syncthreads();
    #pragma unroll
    for (int i = 0; i < T_TILE / 256; ++i) {
        int idx = t0 + i * 256 + tid;
        if (idx < E) atomicAdd(&sh_scan[row[idx] >> NB_SH], 1);
    }
    __syncthreads();
    int x = sh_scan[tid];
    __syncthreads();
    for (int off = 1; off < 256; off <<= 1) {
        int t = (tid >= off) ? sh_scan[tid - off] : 0;
        __syncthreads();
        sh_scan[tid] += t;
        __syncthreads();
    }
    int excl = sh_scan[tid] - x;
    sh_start[tid] = excl;
    sh_cur[tid]   = excl;
    sh_base[tid]  = (x > 0) ? atomicAdd(&bcursor[tid], x) : 0;
    __syncthreads();
    #pragma unroll
    for (int i = 0; i < T_TILE / 256; ++i) {
        int idx = t0 + i * 256 + tid;
        if (idx < E) {
            int   r = row[idx];
            int   c = col[idx];
            float v = val[idx];
            int   b = r >> NB_SH;
            int   p = atomicAdd(&sh_cur[b], 1);
            unsigned lo = (unsigned)(((r & ((1 << NB_SH) - 1)) << 18) | c);
            sh_data[p] = ((long long)__float_as_int(v) << 32) | (long long)lo;
            sh_gpos[p] = sh_base[b] + (p - sh_start[b]);
        }
    }
    __syncthreads();
    int tot = sh_scan[255];
    for (int p = tid; p < tot; p += 256) {
        bedges[sh_gpos[p]] = sh_data[p];
    }
}

// Pass B: one block per bucket; resolve exact CSR slot, write final edges
__global__ __launch_bounds__(1024) void passB(const int* __restrict__ rs,
                                              const long long* __restrict__ bedges,
                                              int* __restrict__ cursor,
                                              int2* __restrict__ edges, int N) {
    int b = blockIdx.x;
    int base = b << NB_SH;
    int endRow = base + (1 << NB_SH);
    if (endRow > N) endRow = N;
    int s = rs[base], e = rs[endRow];
    for (int k = s + threadIdx.x; k < e; k += 1024) {
        long long be = bedges[k];
        unsigned lo = (unsigned)be;
        int r = base + (int)(lo >> 18);
        int c = (int)(lo & 0x3FFFF);
        int pos = atomicAdd(&cursor[r], 1);
        edges[pos] = make_int2(c, (int)(be >> 32));
    }
}

// ---------------- fp32 -> fp16 convert (8 elems/thread, both tables) ----------------

__global__ void f32_to_f16_all(const float* __restrict__ uE, const float* __restrict__ iE,
                               __half* __restrict__ dst, int nu8, int ntot8) {
    int i = blockIdx.x * blockDim.x + threadIdx.x;
    if (i >= ntot8) return;
    const float* src = (i < nu8) ? (uE + (size_t)i * 8)
                                 : (iE + (size_t)(i - nu8) * 8);
    float4 a = ((const float4*)src)[0];
    float4 b = ((const float4*)src)[1];
    __half2 h0 = __floats2half2_rn(a.x, a.y);
    __half2 h1 = __floats2half2_rn(a.z, a.w);
    __half2 h2 = __floats2half2_rn(b.x, b.y);
    __half2 h3 = __floats2half2_rn(b.z, b.w);
    uint4 o;
    o.x = *(unsigned int*)&h0;
    o.y = *(unsigned int*)&h1;
    o.z = *(unsigned int*)&h2;
    o.w = *(unsigned int*)&h3;
    ((uint4*)dst)[i] = o;
}

// ---------------- SpMM: 2 rows/wave (32 lanes each), fp16 h, fp32 acc ----------------

__global__ void spmm_kernel(const int* __restrict__ rs, const int2* __restrict__ edges,
                            const __half* __restrict__ hin, __half* __restrict__ hout,
                            int N) {
    int gid  = blockIdx.x * blockDim.x + threadIdx.x;
    int wave = gid >> 6;
    int lane = threadIdx.x & 63;
    int half = lane >> 5;
    int l32  = lane & 31;
    int row  = wave * 2 + half;
    if (row >= N) return;
    int s = rs[row], e = rs[row + 1];
    float4 acc = make_float4(0.f, 0.f, 0.f, 0.f);
    for (int k = s; k < e; k += CHUNK) {
        uint2 raw[CHUNK];
        float vv[CHUNK];
        #pragma unroll
        for (int j = 0; j < CHUNK; ++j) {
            bool ok  = (k + j) < e;
            int  idx = ok ? (k + j) : s;
            int2 ed  = edges[idx];
            vv[j]    = ok ? __int_as_float(ed.y) : 0.f;
            raw[j]   = *(const uint2*)(hin + (size_t)ed.x * EMBED + 4 * l32);
        }
        #pragma unroll
        for (int j = 0; j < CHUNK; ++j) {
            __half2 h01 = *(__half2*)&raw[j].x;
            __half2 h23 = *(__half2*)&raw[j].y;
            acc.x = fmaf(__half2float(h01.x), vv[j], acc.x);
            acc.y = fmaf(__half2float(h01.y), vv[j], acc.y);
            acc.z = fmaf(__half2float(h23.x), vv[j], acc.z);
            acc.w = fmaf(__half2float(h23.y), vv[j], acc.w);
        }
    }
    __half2 o0 = __floats2half2_rn(acc.x, acc.y);
    __half2 o1 = __floats2half2_rn(acc.z, acc.w);
    uint2 o;
    o.x = *(unsigned int*)&o0;
    o.y = *(unsigned int*)&o1;
    *(uint2*)(hout + (size_t)row * EMBED + 4 * l32) = o;
}

// ---------------- fused tail: per pair b, half0 = u-row, half1 = v-row ----------------
// acc = emb(fp32) + h1 + h2 + (L @ h2)[row]; dot across halves via shfl_xor(32).

__global__ void spmm_pair(const int* __restrict__ rs, const int2* __restrict__ edges,
                          const __half* __restrict__ h1, const __half* __restrict__ h2,
                          const float* __restrict__ uE, const float* __restrict__ iE,
                          const int* __restrict__ uIdx, const int* __restrict__ vIdx,
                          float* __restrict__ out, int B, int userNum) {
    int gid  = blockIdx.x * blockDim.x + threadIdx.x;
    int wave = gid >> 6;
    int lane = threadIdx.x & 63;
    int half = lane >> 5;
    int l32  = lane & 31;
    if (wave >= B) return;
    int row;
    const float* emb;
    if (half == 0) {
        int u = uIdx[wave];
        row = u;
        emb = uE + (size_t)u * EMBED;
    } else {
        int it = vIdx[wave];
        row = userNum + it;
        emb = iE + (size_t)it * EMBED;
    }
    float4 acc = *(const float4*)(emb + 4 * l32);
    size_t ro = (size_t)row * EMBED + 4 * l32;
    uint2 r1 = *(const uint2*)(h1 + ro);
    uint2 r2 = *(const uint2*)(h2 + ro);
    {
        __half2 a0 = *(__half2*)&r1.x, a1 = *(__half2*)&r1.y;
        __half2 b0 = *(__half2*)&r2.x, b1 = *(__half2*)&r2.y;
        acc.x += __half2float(a0.x) + __half2float(b0.x);
        acc.y += __half2float(a0.y) + __half2float(b0.y);
        acc.z += __half2float(a1.x) + __half2float(b1.x);
        acc.w += __half2float(a1.y) + __half2float(b1.y);
    }
    int s = rs[row], e = rs[row + 1];
    for (int k = s; k < e; k += CHUNK) {
        uint2 raw[CHUNK];
        float vv[CHUNK];
        #pragma unroll
        for (int j = 0; j < CHUNK; ++j) {
            bool ok  = (k + j) < e;
            int  idx = ok ? (k + j) : s;
            int2 ed  = edges[idx];
            vv[j]    = ok ? __int_as_float(ed.y) : 0.f;
            raw[j]   = *(const uint2*)(h2 + (size_t)ed.x * EMBED + 4 * l32);
        }
        #pragma unroll
        for (int j = 0; j < CHUNK; ++j) {
            __half2 h01 = *(__half2*)&raw[j].x;
            __half2 h23 = *(__half2*)&raw[j].y;
            acc.x = fmaf(__half2float(h01.x), vv[j], acc.x);
            acc.y = fmaf(__half2float(h01.y), vv[j], acc.y);
            acc.z = fmaf(__half2float(h23.x), vv[j], acc.z);
            acc.w = fmaf(__half2float(h23.y), vv[j], acc.w);
        }
    }
    // cross-half dot: lane l gets the other side's 4 cols
    float ox = __shfl_xor(acc.x, 32);
    float oy = __shfl_xor(acc.y, 32);
    float oz = __shfl_xor(acc.z, 32);
    float ow = __shfl_xor(acc.w, 32);
    float sdot = acc.x * ox + acc.y * oy + acc.z * oz + acc.w * ow;
    #pragma unroll
    for (int off = 16; off > 0; off >>= 1) sdot += __shfl_down(sdot, off, 32);
    // both halves summed the same products -> reduce over full wave doubles it
    sdot += __shfl_down(sdot, 32);
    if (lane == 0) out[wave] = sdot * (1.f / 32.f);   // (acc/4)·(acc/4), x2 halves
}

// ---------------- launch ----------------

extern "C" void kernel_launch(void* const* d_in, const int* in_sizes, int n_in,
                              void* d_out, int out_size, void* d_ws, size_t ws_size,
                              hipStream_t stream) {
    const float* uE      = (const float*)d_in[0];
    const float* iE      = (const float*)d_in[1];
    const float* L_val   = (const float*)d_in[2];
    const int*   L_row   = (const int*)d_in[3];
    const int*   L_col   = (const int*)d_in[4];
    const int*   userIdx = (const int*)d_in[5];
    const int*   itemIdx = (const int*)d_in[6];

    const int userNum = in_sizes[0] / EMBED;   // 100000
    const int itemNum = in_sizes[1] / EMBED;   // 50000
    const int N = userNum + itemNum;           // 150000
    const int E = in_sizes[2];                 // 2000000
    const int B = in_sizes[5];                 // 16384
    float* out = (float*)d_out;

    char* ws = (char*)d_ws;
    size_t off = 0;
    auto alloc = [&](size_t bytes) -> void* {
        void* p = ws + off;
        off += (bytes + 1023) & ~(size_t)1023;
        return p;
    };
    __half* h0     = (__half*)alloc((size_t)N * EMBED * 2);
    __half* h1     = (__half*)alloc((size_t)N * EMBED * 2);
    __half* h2     = (__half*)alloc((size_t)N * EMBED * 2);
    int2*   edges  = (int2*) alloc((size_t)E * 8);
    long long* bedges = (long long*)alloc((size_t)E * 8);
    int*    rs     = (int*)  alloc((size_t)(N + 1) * 4);
    int*    cursor = (int*)  alloc((size_t)N * 4);
    int*    hist   = (int*)  alloc((size_t)N * 4);
    int*    bsums  = (int*)  alloc(8192);
    int*    bcursor= (int*)  alloc(1024);
    (void)off; (void)ws_size; (void)n_in; (void)out_size;

    const int tb = 256;
    const int NBUCKETS = (N + (1 << NB_SH) - 1) >> NB_SH;   // 147 (<=256 required)

    // CSR build: hist -> scan -> bucket sort (passA) -> exact placement (passB)
    (void)hipMemsetAsync(hist, 0, (size_t)N * 4, stream);
    const int E4 = E / 4;
    hist_kernel<<<(E4 + tb - 1) / tb, tb, 0, stream>>>(L_row, hist, E4);
    const int nb = (N + 255) / 256;
    scan1<<<nb, 256, 0, stream>>>(hist, rs, bsums, N);
    scan2<<<1, 1024, 0, stream>>>(bsums, nb);
    scan3<<<(N + tb - 1) / tb, tb, 0, stream>>>(rs, bsums, cursor, N, E);
    binit<<<1, 256, 0, stream>>>(rs, bcursor, N, NBUCKETS);
    passA<<<(E + T_TILE - 1) / T_TILE, 256, 0, stream>>>(L_row, L_col, L_val,
                                                         bcursor, bedges, E);
    passB<<<NBUCKETS, 1024, 0, stream>>>(rs, bedges, cursor, edges, N);

    // feats -> fp16 (single launch)
    const int nu8 = userNum * EMBED / 8;
    const int ntot8 = N * EMBED / 8;
    f32_to_f16_all<<<(ntot8 + tb - 1) / tb, tb, 0, stream>>>(uE, iE, h0, nu8, ntot8);

    // propagation
    const int spmm_blocks = (N + 7) / 8;        // 8 rows per 256-thread block
    spmm_kernel<<<spmm_blocks, 256, 0, stream>>>(rs, edges, h0, h1, N);
    spmm_kernel<<<spmm_blocks, 256, 0, stream>>>(rs, edges, h1, h2, N);

    // fused layer-3-restricted spmm + layer-sum + dot
    spmm_pair<<<(B + 3) / 4, 256, 0, stream>>>(rs, edges, h1, h2, uE, iE,
                                               userIdx, itemIdx, out, B, userNum);
}

// Round 9
// 480.835 us; speedup vs baseline: 1.3621x; 1.1455x over previous
//
#include <hip/hip_runtime.h>
#include <hip/hip_fp16.h>

#define EMBED 128
#define CHUNK 6             // spmm gather depth (keep VGPR <= 64)
#define PCHUNK 8            // spmm_pair gather depth (uint2 path)
#define T_TILE 4096
#define NB_SH 10            // 1024 rows per bucket
#define BCAP 32768          // fixed per-bucket capacity (avg ~13.6K, 50-sigma slack)

// ---------------- CSR build: passA (bucket sort, fixed-cap regions) ----------------

__global__ __launch_bounds__(256) void passA(const int* __restrict__ row,
                                             const int* __restrict__ col,
                                             const float* __restrict__ val,
                                             int* __restrict__ bcnt,
                                             long long* __restrict__ bedges, int E) {
    __shared__ int sh_scan[256];
    __shared__ int sh_start[256];
    __shared__ int sh_cur[256];
    __shared__ int sh_base[256];   // global (fixed-region) base per bucket
    __shared__ long long sh_data[T_TILE];
    __shared__ int sh_gpos[T_TILE];
    const int t0  = blockIdx.x * T_TILE;
    const int tid = threadIdx.x;

    sh_scan[tid] = 0;
    __syncthreads();
    #pragma unroll
    for (int i = 0; i < T_TILE / 256; ++i) {
        int idx = t0 + i * 256 + tid;
        if (idx < E) atomicAdd(&sh_scan[row[idx] >> NB_SH], 1);
    }
    __syncthreads();
    int x = sh_scan[tid];
    __syncthreads();
    for (int off = 1; off < 256; off <<= 1) {
        int t = (tid >= off) ? sh_scan[tid - off] : 0;
        __syncthreads();
        sh_scan[tid] += t;
        __syncthreads();
    }
    int excl = sh_scan[tid] - x;
    sh_start[tid] = excl;
    sh_cur[tid]   = excl;
    sh_base[tid]  = (x > 0) ? (tid * BCAP + atomicAdd(&bcnt[tid], x)) : 0;
    __syncthreads();
    #pragma unroll
    for (int i = 0; i < T_TILE / 256; ++i) {
        int idx = t0 + i * 256 + tid;
        if (idx < E) {
            int   r = row[idx];
            int   c = col[idx];
            float v = val[idx];
            int   b = r >> NB_SH;
            int   p = atomicAdd(&sh_cur[b], 1);
            unsigned lo = (unsigned)(((r & ((1 << NB_SH) - 1)) << 18) | c);
            sh_data[p] = ((long long)__float_as_int(v) << 32) | (long long)lo;
            sh_gpos[p] = sh_base[b] + (p - sh_start[b]);
        }
    }
    __syncthreads();
    int tot = sh_scan[255];
    for (int p = tid; p < tot; p += 256) {
        bedges[sh_gpos[p]] = sh_data[p];
    }
}

// ---------------- passB: per-bucket row hist + scan -> rs + exact placement ----------
// One 1024-thread block per bucket. Replaces global hist/scan1/scan2/scan3/binit and
// the global-cursor scatter.

__global__ __launch_bounds__(1024) void passB(const long long* __restrict__ bedges,
                                              const int* __restrict__ bcnt,
                                              int* __restrict__ rs,
                                              int2* __restrict__ edges,
                                              int N, int E, int nbuckets) {
    __shared__ int sh_hist[1024];   // row hist, then reused as cursor
    __shared__ int sh_scan[1024];
    __shared__ int sh_bc[256];
    __shared__ int sh_gbase;
    const int b    = blockIdx.x;
    const int tid  = threadIdx.x;
    const int base = b << NB_SH;
    const int cnt  = bcnt[b];
    const long long* seg = bedges + (size_t)b * BCAP;

    sh_hist[tid] = 0;
    if (tid < nbuckets) sh_bc[tid] = bcnt[tid];
    __syncthreads();
    if (tid == 0) {
        int g = 0;
        for (int j = 0; j < b; ++j) g += sh_bc[j];
        sh_gbase = g;
    }
    for (int k = tid; k < cnt; k += 1024) {
        unsigned lo = (unsigned)seg[k];
        atomicAdd(&sh_hist[lo >> 18], 1);
    }
    __syncthreads();
    int x = sh_hist[tid];
    sh_scan[tid] = x;
    __syncthreads();
    for (int off = 1; off < 1024; off <<= 1) {
        int t = (tid >= off) ? sh_scan[tid - off] : 0;
        __syncthreads();
        sh_scan[tid] += t;
        __syncthreads();
    }
    int excl = sh_scan[tid] - x;
    int gbase = sh_gbase;
    int rrow = base + tid;
    if (rrow < N) rs[rrow] = gbase + excl;
    if (b == nbuckets - 1 && tid == 0) rs[N] = E;
    // reuse hist as bucket-local cursor
    sh_hist[tid] = excl;
    __syncthreads();
    for (int k = tid; k < cnt; k += 1024) {
        long long be = seg[k];
        unsigned lo = (unsigned)be;
        int p = atomicAdd(&sh_hist[lo >> 18], 1);
        edges[gbase + p] = make_int2((int)(lo & 0x3FFFF), (int)(be >> 32));
    }
}

// ---------------- fp32 -> fp16 convert (8 elems/thread, both tables) ----------------

__global__ void f32_to_f16_all(const float* __restrict__ uE, const float* __restrict__ iE,
                               __half* __restrict__ dst, int nu8, int ntot8) {
    int i = blockIdx.x * blockDim.x + threadIdx.x;
    if (i >= ntot8) return;
    const float* src = (i < nu8) ? (uE + (size_t)i * 8)
                                 : (iE + (size_t)(i - nu8) * 8);
    float4 a = ((const float4*)src)[0];
    float4 b = ((const float4*)src)[1];
    __half2 h0 = __floats2half2_rn(a.x, a.y);
    __half2 h1 = __floats2half2_rn(a.z, a.w);
    __half2 h2 = __floats2half2_rn(b.x, b.y);
    __half2 h3 = __floats2half2_rn(b.z, b.w);
    uint4 o;
    o.x = *(unsigned int*)&h0;
    o.y = *(unsigned int*)&h1;
    o.z = *(unsigned int*)&h2;
    o.w = *(unsigned int*)&h3;
    ((uint4*)dst)[i] = o;
}

// ---------------- SpMM: 4 rows/wave (16 lanes each), uint4 gathers, fp32 acc --------
// Per edge: one 256B gather via 16 lanes x 16B; 8 cols/lane.

__global__ __launch_bounds__(256, 8) void spmm_kernel(const int* __restrict__ rs,
                                                      const int2* __restrict__ edges,
                                                      const __half* __restrict__ hin,
                                                      __half* __restrict__ hout, int N) {
    int gid  = blockIdx.x * blockDim.x + threadIdx.x;
    int wave = gid >> 6;
    int lane = threadIdx.x & 63;
    int q    = lane >> 4;        // quarter: 0..3
    int l16  = lane & 15;
    int row  = wave * 4 + q;
    int rr   = (row < N) ? row : N - 1;
    int s = rs[rr], e = rs[rr + 1];
    float acc[8] = {0.f, 0.f, 0.f, 0.f, 0.f, 0.f, 0.f, 0.f};
    for (int k = s; k < e; k += CHUNK) {
        uint4 raw[CHUNK];
        float vv[CHUNK];
        #pragma unroll
        for (int j = 0; j < CHUNK; ++j) {
            bool ok  = (k + j) < e;
            int  idx = ok ? (k + j) : s;
            int2 ed  = edges[idx];
            vv[j]    = ok ? __int_as_float(ed.y) : 0.f;
            raw[j]   = *(const uint4*)(hin + (size_t)ed.x * EMBED + 8 * l16);
        }
        #pragma unroll
        for (int j = 0; j < CHUNK; ++j) {
            __half2 p0 = *(__half2*)&raw[j].x;
            __half2 p1 = *(__half2*)&raw[j].y;
            __half2 p2 = *(__half2*)&raw[j].z;
            __half2 p3 = *(__half2*)&raw[j].w;
            acc[0] = fmaf(__half2float(p0.x), vv[j], acc[0]);
            acc[1] = fmaf(__half2float(p0.y), vv[j], acc[1]);
            acc[2] = fmaf(__half2float(p1.x), vv[j], acc[2]);
            acc[3] = fmaf(__half2float(p1.y), vv[j], acc[3]);
            acc[4] = fmaf(__half2float(p2.x), vv[j], acc[4]);
            acc[5] = fmaf(__half2float(p2.y), vv[j], acc[5]);
            acc[6] = fmaf(__half2float(p3.x), vv[j], acc[6]);
            acc[7] = fmaf(__half2float(p3.y), vv[j], acc[7]);
        }
    }
    if (row < N) {
        __half2 o0 = __floats2half2_rn(acc[0], acc[1]);
        __half2 o1 = __floats2half2_rn(acc[2], acc[3]);
        __half2 o2 = __floats2half2_rn(acc[4], acc[5]);
        __half2 o3 = __floats2half2_rn(acc[6], acc[7]);
        uint4 o;
        o.x = *(unsigned int*)&o0;
        o.y = *(unsigned int*)&o1;
        o.z = *(unsigned int*)&o2;
        o.w = *(unsigned int*)&o3;
        *(uint4*)(hout + (size_t)row * EMBED + 8 * l16) = o;
    }
}

// ---------------- fused tail: per pair b, half0 = u-row, half1 = v-row ----------------

__global__ void spmm_pair(const int* __restrict__ rs, const int2* __restrict__ edges,
                          const __half* __restrict__ h1, const __half* __restrict__ h2,
                          const float* __restrict__ uE, const float* __restrict__ iE,
                          const int* __restrict__ uIdx, const int* __restrict__ vIdx,
                          float* __restrict__ out, int B, int userNum) {
    int gid  = blockIdx.x * blockDim.x + threadIdx.x;
    int wave = gid >> 6;
    int lane = threadIdx.x & 63;
    int half = lane >> 5;
    int l32  = lane & 31;
    if (wave >= B) return;
    int row;
    const float* emb;
    if (half == 0) {
        int u = uIdx[wave];
        row = u;
        emb = uE + (size_t)u * EMBED;
    } else {
        int it = vIdx[wave];
        row = userNum + it;
        emb = iE + (size_t)it * EMBED;
    }
    float4 acc = *(const float4*)(emb + 4 * l32);
    size_t ro = (size_t)row * EMBED + 4 * l32;
    uint2 r1 = *(const uint2*)(h1 + ro);
    uint2 r2 = *(const uint2*)(h2 + ro);
    {
        __half2 a0 = *(__half2*)&r1.x, a1 = *(__half2*)&r1.y;
        __half2 b0 = *(__half2*)&r2.x, b1 = *(__half2*)&r2.y;
        acc.x += __half2float(a0.x) + __half2float(b0.x);
        acc.y += __half2float(a0.y) + __half2float(b0.y);
        acc.z += __half2float(a1.x) + __half2float(b1.x);
        acc.w += __half2float(a1.y) + __half2float(b1.y);
    }
    int s = rs[row], e = rs[row + 1];
    for (int k = s; k < e; k += PCHUNK) {
        uint2 raw[PCHUNK];
        float vv[PCHUNK];
        #pragma unroll
        for (int j = 0; j < PCHUNK; ++j) {
            bool ok  = (k + j) < e;
            int  idx = ok ? (k + j) : s;
            int2 ed  = edges[idx];
            vv[j]    = ok ? __int_as_float(ed.y) : 0.f;
            raw[j]   = *(const uint2*)(h2 + (size_t)ed.x * EMBED + 4 * l32);
        }
        #pragma unroll
        for (int j = 0; j < PCHUNK; ++j) {
            __half2 h01 = *(__half2*)&raw[j].x;
            __half2 h23 = *(__half2*)&raw[j].y;
            acc.x = fmaf(__half2float(h01.x), vv[j], acc.x);
            acc.y = fmaf(__half2float(h01.y), vv[j], acc.y);
            acc.z = fmaf(__half2float(h23.x), vv[j], acc.z);
            acc.w = fmaf(__half2float(h23.y), vv[j], acc.w);
        }
    }
    float ox = __shfl_xor(acc.x, 32);
    float oy = __shfl_xor(acc.y, 32);
    float oz = __shfl_xor(acc.z, 32);
    float ow = __shfl_xor(acc.w, 32);
    float sdot = acc.x * ox + acc.y * oy + acc.z * oz + acc.w * ow;
    #pragma unroll
    for (int off = 16; off > 0; off >>= 1) sdot += __shfl_down(sdot, off, 32);
    sdot += __shfl_down(sdot, 32);
    if (lane == 0) out[wave] = sdot * (1.f / 32.f);   // (acc/4)·(acc/4), x2 halves
}

// ---------------- launch ----------------

extern "C" void kernel_launch(void* const* d_in, const int* in_sizes, int n_in,
                              void* d_out, int out_size, void* d_ws, size_t ws_size,
                              hipStream_t stream) {
    const float* uE      = (const float*)d_in[0];
    const float* iE      = (const float*)d_in[1];
    const float* L_val   = (const float*)d_in[2];
    const int*   L_row   = (const int*)d_in[3];
    const int*   L_col   = (const int*)d_in[4];
    const int*   userIdx = (const int*)d_in[5];
    const int*   itemIdx = (const int*)d_in[6];

    const int userNum = in_sizes[0] / EMBED;   // 100000
    const int itemNum = in_sizes[1] / EMBED;   // 50000
    const int N = userNum + itemNum;           // 150000
    const int E = in_sizes[2];                 // 2000000
    const int B = in_sizes[5];                 // 16384
    float* out = (float*)d_out;

    char* ws = (char*)d_ws;
    size_t off = 0;
    auto alloc = [&](size_t bytes) -> void* {
        void* p = ws + off;
        off += (bytes + 1023) & ~(size_t)1023;
        return p;
    };
    const int NBUCKETS = (N + (1 << NB_SH) - 1) >> NB_SH;   // 147
    __half* h0     = (__half*)alloc((size_t)N * EMBED * 2);
    __half* h1     = (__half*)alloc((size_t)N * EMBED * 2);
    __half* h2     = (__half*)alloc((size_t)N * EMBED * 2);
    int2*   edges  = (int2*) alloc((size_t)E * 8);
    long long* bedges = (long long*)alloc((size_t)NBUCKETS * BCAP * 8);
    int*    rs     = (int*)  alloc((size_t)(N + 1) * 4);
    int*    bcnt   = (int*)  alloc(1024);
    (void)off; (void)ws_size; (void)n_in; (void)out_size;

    const int tb = 256;

    // CSR build: 3 dispatches
    (void)hipMemsetAsync(bcnt, 0, 1024, stream);
    passA<<<(E + T_TILE - 1) / T_TILE, 256, 0, stream>>>(L_row, L_col, L_val,
                                                         bcnt, bedges, E);
    passB<<<NBUCKETS, 1024, 0, stream>>>(bedges, bcnt, rs, edges, N, E, NBUCKETS);

    // feats -> fp16 (single launch)
    const int nu8 = userNum * EMBED / 8;
    const int ntot8 = N * EMBED / 8;
    f32_to_f16_all<<<(ntot8 + tb - 1) / tb, tb, 0, stream>>>(uE, iE, h0, nu8, ntot8);

    // propagation: 16 rows per 256-thread block (4 rows/wave)
    const int spmm_blocks = (N + 15) / 16;
    spmm_kernel<<<spmm_blocks, 256, 0, stream>>>(rs, edges, h0, h1, N);
    spmm_kernel<<<spmm_blocks, 256, 0, stream>>>(rs, edges, h1, h2, N);

    // fused layer-3-restricted spmm + layer-sum + dot
    spmm_pair<<<(B + 3) / 4, 256, 0, stream>>>(rs, edges, h1, h2, uE, iE,
                                               userIdx, itemIdx, out, B, userNum);
}

// Round 10
// 423.709 us; speedup vs baseline: 1.5457x; 1.1348x over previous
//
#include <hip/hip_runtime.h>
#include <hip/hip_fp16.h>

#define EMBED 128
#define CHUNK 8             // spmm gather depth (uint2 path; 16+8+4 regs fits, VGPR~32)
#define T_TILE 4096
#define NB_SH 10            // 1024 rows per bucket
#define BCAP 32768          // fixed per-bucket capacity (avg ~13.6K)

// ---------------- CSR build: passA (bucket sort, fixed-cap regions) ----------------

__global__ __launch_bounds__(256) void passA(const int* __restrict__ row,
                                             const int* __restrict__ col,
                                             const float* __restrict__ val,
                                             int* __restrict__ bcnt,
                                             long long* __restrict__ bedges, int E) {
    __shared__ int sh_scan[256];
    __shared__ int sh_start[256];
    __shared__ int sh_cur[256];
    __shared__ int sh_base[256];   // global (fixed-region) base per bucket
    __shared__ long long sh_data[T_TILE];
    __shared__ int sh_gpos[T_TILE];
    const int t0  = blockIdx.x * T_TILE;
    const int tid = threadIdx.x;

    sh_scan[tid] = 0;
    __syncthreads();
    #pragma unroll
    for (int i = 0; i < T_TILE / 256; ++i) {
        int idx = t0 + i * 256 + tid;
        if (idx < E) atomicAdd(&sh_scan[row[idx] >> NB_SH], 1);
    }
    __syncthreads();
    int x = sh_scan[tid];
    __syncthreads();
    for (int off = 1; off < 256; off <<= 1) {
        int t = (tid >= off) ? sh_scan[tid - off] : 0;
        __syncthreads();
        sh_scan[tid] += t;
        __syncthreads();
    }
    int excl = sh_scan[tid] - x;
    sh_start[tid] = excl;
    sh_cur[tid]   = excl;
    sh_base[tid]  = (x > 0) ? (tid * BCAP + atomicAdd(&bcnt[tid], x)) : 0;
    __syncthreads();
    #pragma unroll
    for (int i = 0; i < T_TILE / 256; ++i) {
        int idx = t0 + i * 256 + tid;
        if (idx < E) {
            int   r = row[idx];
            int   c = col[idx];
            float v = val[idx];
            int   b = r >> NB_SH;
            int   p = atomicAdd(&sh_cur[b], 1);
            unsigned lo = (unsigned)(((r & ((1 << NB_SH) - 1)) << 18) | c);
            sh_data[p] = ((long long)__float_as_int(v) << 32) | (long long)lo;
            sh_gpos[p] = sh_base[b] + (p - sh_start[b]);
        }
    }
    __syncthreads();
    int tot = sh_scan[255];
    for (int p = tid; p < tot; p += 256) {
        bedges[sh_gpos[p]] = sh_data[p];
    }
}

// ---------------- passB: per-bucket row hist + scan -> rs + exact placement ----------

__global__ __launch_bounds__(1024) void passB(const long long* __restrict__ bedges,
                                              const int* __restrict__ bcnt,
                                              int* __restrict__ rs,
                                              int2* __restrict__ edges,
                                              int N, int E, int nbuckets) {
    __shared__ int sh_hist[1024];   // row hist, then reused as cursor
    __shared__ int sh_scan[1024];
    __shared__ int sh_bc[256];
    __shared__ int sh_gbase;
    const int b    = blockIdx.x;
    const int tid  = threadIdx.x;
    const int base = b << NB_SH;
    const int cnt  = bcnt[b];
    const long long* seg = bedges + (size_t)b * BCAP;

    sh_hist[tid] = 0;
    if (tid < nbuckets) sh_bc[tid] = bcnt[tid];
    __syncthreads();
    if (tid == 0) {
        int g = 0;
        for (int j = 0; j < b; ++j) g += sh_bc[j];
        sh_gbase = g;
    }
    for (int k = tid; k < cnt; k += 1024) {
        unsigned lo = (unsigned)seg[k];
        atomicAdd(&sh_hist[lo >> 18], 1);
    }
    __syncthreads();
    int x = sh_hist[tid];
    sh_scan[tid] = x;
    __syncthreads();
    for (int off = 1; off < 1024; off <<= 1) {
        int t = (tid >= off) ? sh_scan[tid - off] : 0;
        __syncthreads();
        sh_scan[tid] += t;
        __syncthreads();
    }
    int excl = sh_scan[tid] - x;
    int gbase = sh_gbase;
    int rrow = base + tid;
    if (rrow < N) rs[rrow] = gbase + excl;
    if (b == nbuckets - 1 && tid == 0) rs[N] = E;
    sh_hist[tid] = excl;
    __syncthreads();
    for (int k = tid; k < cnt; k += 1024) {
        long long be = seg[k];
        unsigned lo = (unsigned)be;
        int p = atomicAdd(&sh_hist[lo >> 18], 1);
        edges[gbase + p] = make_int2((int)(lo & 0x3FFFF), (int)(be >> 32));
    }
}

// ---------------- fp32 -> fp16 convert (8 elems/thread, both tables) ----------------

__global__ void f32_to_f16_all(const float* __restrict__ uE, const float* __restrict__ iE,
                               __half* __restrict__ dst, int nu8, int ntot8) {
    int i = blockIdx.x * blockDim.x + threadIdx.x;
    if (i >= ntot8) return;
    const float* src = (i < nu8) ? (uE + (size_t)i * 8)
                                 : (iE + (size_t)(i - nu8) * 8);
    float4 a = ((const float4*)src)[0];
    float4 b = ((const float4*)src)[1];
    __half2 h0 = __floats2half2_rn(a.x, a.y);
    __half2 h1 = __floats2half2_rn(a.z, a.w);
    __half2 h2 = __floats2half2_rn(b.x, b.y);
    __half2 h3 = __floats2half2_rn(b.z, b.w);
    uint4 o;
    o.x = *(unsigned int*)&h0;
    o.y = *(unsigned int*)&h1;
    o.z = *(unsigned int*)&h2;
    o.w = *(unsigned int*)&h3;
    ((uint4*)dst)[i] = o;
}

// ---------------- SpMM: 2 rows/wave (32 lanes each), fp16 h, fp32 acc ----------------
// R8-proven config: uint2/lane gathers, CHUNK=8, VGPR~32, occ ~72%.

__global__ void spmm_kernel(const int* __restrict__ rs, const int2* __restrict__ edges,
                            const __half* __restrict__ hin, __half* __restrict__ hout,
                            int N) {
    int gid  = blockIdx.x * blockDim.x + threadIdx.x;
    int wave = gid >> 6;
    int lane = threadIdx.x & 63;
    int half = lane >> 5;
    int l32  = lane & 31;
    int row  = wave * 2 + half;
    if (row >= N) return;
    int s = rs[row], e = rs[row + 1];
    float4 acc = make_float4(0.f, 0.f, 0.f, 0.f);
    for (int k = s; k < e; k += CHUNK) {
        uint2 raw[CHUNK];
        float vv[CHUNK];
        #pragma unroll
        for (int j = 0; j < CHUNK; ++j) {
            bool ok  = (k + j) < e;
            int  idx = ok ? (k + j) : s;
            int2 ed  = edges[idx];
            vv[j]    = ok ? __int_as_float(ed.y) : 0.f;
            raw[j]   = *(const uint2*)(hin + (size_t)ed.x * EMBED + 4 * l32);
        }
        #pragma unroll
        for (int j = 0; j < CHUNK; ++j) {
            __half2 h01 = *(__half2*)&raw[j].x;
            __half2 h23 = *(__half2*)&raw[j].y;
            acc.x = fmaf(__half2float(h01.x), vv[j], acc.x);
            acc.y = fmaf(__half2float(h01.y), vv[j], acc.y);
            acc.z = fmaf(__half2float(h23.x), vv[j], acc.z);
            acc.w = fmaf(__half2float(h23.y), vv[j], acc.w);
        }
    }
    __half2 o0 = __floats2half2_rn(acc.x, acc.y);
    __half2 o1 = __floats2half2_rn(acc.z, acc.w);
    uint2 o;
    o.x = *(unsigned int*)&o0;
    o.y = *(unsigned int*)&o1;
    *(uint2*)(hout + (size_t)row * EMBED + 4 * l32) = o;
}

// ---------------- fused tail: per pair b, half0 = u-row, half1 = v-row ----------------

__global__ void spmm_pair(const int* __restrict__ rs, const int2* __restrict__ edges,
                          const __half* __restrict__ h1, const __half* __restrict__ h2,
                          const float* __restrict__ uE, const float* __restrict__ iE,
                          const int* __restrict__ uIdx, const int* __restrict__ vIdx,
                          float* __restrict__ out, int B, int userNum) {
    int gid  = blockIdx.x * blockDim.x + threadIdx.x;
    int wave = gid >> 6;
    int lane = threadIdx.x & 63;
    int half = lane >> 5;
    int l32  = lane & 31;
    if (wave >= B) return;
    int row;
    const float* emb;
    if (half == 0) {
        int u = uIdx[wave];
        row = u;
        emb = uE + (size_t)u * EMBED;
    } else {
        int it = vIdx[wave];
        row = userNum + it;
        emb = iE + (size_t)it * EMBED;
    }
    float4 acc = *(const float4*)(emb + 4 * l32);
    size_t ro = (size_t)row * EMBED + 4 * l32;
    uint2 r1 = *(const uint2*)(h1 + ro);
    uint2 r2 = *(const uint2*)(h2 + ro);
    {
        __half2 a0 = *(__half2*)&r1.x, a1 = *(__half2*)&r1.y;
        __half2 b0 = *(__half2*)&r2.x, b1 = *(__half2*)&r2.y;
        acc.x += __half2float(a0.x) + __half2float(b0.x);
        acc.y += __half2float(a0.y) + __half2float(b0.y);
        acc.z += __half2float(a1.x) + __half2float(b1.x);
        acc.w += __half2float(a1.y) + __half2float(b1.y);
    }
    int s = rs[row], e = rs[row + 1];
    for (int k = s; k < e; k += CHUNK) {
        uint2 raw[CHUNK];
        float vv[CHUNK];
        #pragma unroll
        for (int j = 0; j < CHUNK; ++j) {
            bool ok  = (k + j) < e;
            int  idx = ok ? (k + j) : s;
            int2 ed  = edges[idx];
            vv[j]    = ok ? __int_as_float(ed.y) : 0.f;
            raw[j]   = *(const uint2*)(h2 + (size_t)ed.x * EMBED + 4 * l32);
        }
        #pragma unroll
        for (int j = 0; j < CHUNK; ++j) {
            __half2 h01 = *(__half2*)&raw[j].x;
            __half2 h23 = *(__half2*)&raw[j].y;
            acc.x = fmaf(__half2float(h01.x), vv[j], acc.x);
            acc.y = fmaf(__half2float(h01.y), vv[j], acc.y);
            acc.z = fmaf(__half2float(h23.x), vv[j], acc.z);
            acc.w = fmaf(__half2float(h23.y), vv[j], acc.w);
        }
    }
    float ox = __shfl_xor(acc.x, 32);
    float oy = __shfl_xor(acc.y, 32);
    float oz = __shfl_xor(acc.z, 32);
    float ow = __shfl_xor(acc.w, 32);
    float sdot = acc.x * ox + acc.y * oy + acc.z * oz + acc.w * ow;
    #pragma unroll
    for (int off = 16; off > 0; off >>= 1) sdot += __shfl_down(sdot, off, 32);
    sdot += __shfl_down(sdot, 32);
    if (lane == 0) out[wave] = sdot * (1.f / 32.f);   // (acc/4)·(acc/4), x2 halves
}

// ---------------- launch ----------------

extern "C" void kernel_launch(void* const* d_in, const int* in_sizes, int n_in,
                              void* d_out, int out_size, void* d_ws, size_t ws_size,
                              hipStream_t stream) {
    const float* uE      = (const float*)d_in[0];
    const float* iE      = (const float*)d_in[1];
    const float* L_val   = (const float*)d_in[2];
    const int*   L_row   = (const int*)d_in[3];
    const int*   L_col   = (const int*)d_in[4];
    const int*   userIdx = (const int*)d_in[5];
    const int*   itemIdx = (const int*)d_in[6];

    const int userNum = in_sizes[0] / EMBED;   // 100000
    const int itemNum = in_sizes[1] / EMBED;   // 50000
    const int N = userNum + itemNum;           // 150000
    const int E = in_sizes[2];                 // 2000000
    const int B = in_sizes[5];                 // 16384
    float* out = (float*)d_out;

    char* ws = (char*)d_ws;
    size_t off = 0;
    auto alloc = [&](size_t bytes) -> void* {
        void* p = ws + off;
        off += (bytes + 1023) & ~(size_t)1023;
        return p;
    };
    const int NBUCKETS = (N + (1 << NB_SH) - 1) >> NB_SH;   // 147
    __half* h0     = (__half*)alloc((size_t)N * EMBED * 2);
    __half* h1     = (__half*)alloc((size_t)N * EMBED * 2);
    __half* h2     = (__half*)alloc((size_t)N * EMBED * 2);
    int2*   edges  = (int2*) alloc((size_t)E * 8);
    long long* bedges = (long long*)alloc((size_t)NBUCKETS * BCAP * 8);
    int*    rs     = (int*)  alloc((size_t)(N + 1) * 4);
    int*    bcnt   = (int*)  alloc(1024);
    (void)off; (void)ws_size; (void)n_in; (void)out_size;

    const int tb = 256;

    // CSR build: 3 dispatches
    (void)hipMemsetAsync(bcnt, 0, 1024, stream);
    passA<<<(E + T_TILE - 1) / T_TILE, 256, 0, stream>>>(L_row, L_col, L_val,
                                                         bcnt, bedges, E);
    passB<<<NBUCKETS, 1024, 0, stream>>>(bedges, bcnt, rs, edges, N, E, NBUCKETS);

    // feats -> fp16 (single launch)
    const int nu8 = userNum * EMBED / 8;
    const int ntot8 = N * EMBED / 8;
    f32_to_f16_all<<<(ntot8 + tb - 1) / tb, tb, 0, stream>>>(uE, iE, h0, nu8, ntot8);

    // propagation: 8 rows per 256-thread block (2 rows/wave)
    const int spmm_blocks = (N + 7) / 8;
    spmm_kernel<<<spmm_blocks, 256, 0, stream>>>(rs, edges, h0, h1, N);
    spmm_kernel<<<spmm_blocks, 256, 0, stream>>>(rs, edges, h1, h2, N);

    // fused layer-3-restricted spmm + layer-sum + dot
    spmm_pair<<<(B + 3) / 4, 256, 0, stream>>>(rs, edges, h1, h2, uE, iE,
                                               userIdx, itemIdx, out, B, userNum);
}